// Round 6
// baseline (444.088 us; speedup 1.0000x reference)
//
#include <hip/hip_runtime.h>

// out = att @ h  with att = where(adj>0, s1[i]+s2[j], -9e15).
// out[i,k] = -9e15 * (T[k] - Am[i,k]),  Am = (adj>0) @ h,  T = colsum(h)
//
// R12 = R10/R11 with asm constraints the gfx950 backend accepts: waits are
// operand-free ("memory" clobber) + __builtin_amdgcn_sched_barrier(0)
// (rule #18: the barrier, not the clobber, stops MFMA/VALU hoisting above
// the wait). Backend rejects tied ("+v") and input ("v") VECTOR operands
// on asm; vector OUTPUTS ("=v") are fine (the loads compiled).
//
// R10 theory: R8/R9 both land k3 ~146us (~2700 cyc per ~170-cyc iter)
// despite occupancy x2 and VALU /2 => compiler-scheduled loads serialize.
// Fix: ALL main-loop VMEM is volatile inline asm with HAND-COUNTED
// s_waitcnt vmcnt(N) (T3/T4, never 0):
//  - B: 4 slots, 4 iters deep; steady waits vmcnt(16)/(12).
//  - bm: ping-pong sets, 1 block (8 iters) ahead; retired by the ITER0
//    (first block) / ITER4 (steady) waits — counts traced below.
//  - compiler emits no vmem loads in the loop => its waitcnt pass has
//    nothing to drain; final operand-free vmcnt(0) + sched_barrier before
//    the epilogue.
// Volatile asm statements keep mutual program order, so the issue order
// (and thus the vmcnt arithmetic) is exact.
// Unconditional tail prefetches read workspace padding (verified: B tail
// ends < ws+5.3MB, T at +6MB; bm tail ends ~ws+16MB+300B; ws >= 72MB).
// Geometry/expansion/epilogue identical to R9 (harness-verified).
//
// Bitmask format (per row, 32 blocks of 256 j): block b = 4 u64 [c=0..3],
// bit l of u64 c = adj[i][b*256 + 4l + c]  (ballot over int4 lanes).

#define NEG_BIG (-9000000000000000.0f)

typedef __bf16 bf16x8 __attribute__((ext_vector_type(8)));
typedef float f32x16 __attribute__((ext_vector_type(16)));

static __device__ __forceinline__ unsigned short f2bf(float f) {
  unsigned u = __builtin_bit_cast(unsigned, f);
  u = u + 0x7FFFu + ((u >> 16) & 1u);   // RNE
  return (unsigned short)(u >> 16);
}
static __device__ __forceinline__ float bfbits2f(unsigned hi16) {
  return __builtin_bit_cast(float, hi16 << 16);
}
static __device__ __forceinline__ unsigned pk2(float a, float b) {
  return (unsigned)f2bf(a) | ((unsigned)f2bf(b) << 16);
}
static __device__ __forceinline__ bf16x8 asbf(int4 q) {
  return __builtin_bit_cast(bf16x8, q);
}
static __device__ __forceinline__ f32x16 mfma(bf16x8 a, int4 b, f32x16 c) {
  return __builtin_amdgcn_mfma_f32_32x32x16_bf16(a, asbf(b), c, 0, 0, 0);
}

// K0: adj -> bitmask. Wave = one row pass; lane l reads int4 (4 j), 4
// ballots produce 256 j bits per iter. 8192 waves, 32 iters each, 32w/CU.
__global__ __launch_bounds__(256) void k0_bits(const int* __restrict__ adj,
    unsigned long long* __restrict__ bm) {
  const int w = threadIdx.x >> 6, l = threadIdx.x & 63;
  const int row = blockIdx.x * 4 + w;
  const int4* ar = (const int4*)(adj + (size_t)row * 8192) + l;
  unsigned long long* br = bm + (size_t)row * 128;
#pragma unroll 2
  for (int b = 0; b < 32; ++b) {
    int4 v = ar[b * 64];
    unsigned long long b0 = __ballot(v.x > 0);
    unsigned long long b1 = __ballot(v.y > 0);
    unsigned long long b2 = __ballot(v.z > 0);
    unsigned long long b3 = __ballot(v.w > 0);
    if (l == 0) {
      ulonglong2* p = (ulonglong2*)(br + (size_t)b * 4);
      p[0] = make_ulonglong2(b0, b1);
      p[1] = make_ulonglong2(b2, b3);
    }
  }
}

// K1a: WT[n][k] = bf16(W[k][n]); W is 512x256 row-major. Also zeroes T.
__global__ void k1a_wt(const float* __restrict__ W, unsigned short* __restrict__ WT,
                       float* __restrict__ T) {
  const int i = blockIdx.x * 256 + threadIdx.x;
  const int k = i >> 8, n = i & 255;
  WT[n * 512 + k] = f2bf(W[i]);
  if (blockIdx.x == 0) T[threadIdx.x] = 0.f;
}

// K1b: h = x @ W. x tile (32 rows x 512 k) staged through LDS in
// fragment-ready bf16 layout, then 32 MFMA k-steps. Panel slots are
// PERMUTED: physical row mm -> slot ((mm>>1)&1)*16 + (mm&1)*8 + (mm>>2)
// so k3's A-frag = consecutive bits of one ballot dword.
__global__ __launch_bounds__(256) void k1b_h(const float* __restrict__ x,
    const unsigned short* __restrict__ WT, unsigned short* __restrict__ hP) {
  __shared__ unsigned short XS[64 * 264];
  const int t = threadIdx.x;
  const int mt = blockIdx.x;
  const int m0 = mt << 5;
  const int row = t >> 3, c7 = t & 7;
  const float* xr = x + (size_t)(m0 + row) * 512 + c7 * 4;
  const int gb = c7 >> 1, off = (t & 1) * 4;
#pragma unroll
  for (int j = 0; j < 16; ++j) {
    float4 v = *(const float4*)(xr + 32 * j);
    *(uint2*)&XS[(gb + 4 * j) * 264 + row * 8 + off] =
        make_uint2(pk2(v.x, v.y), pk2(v.z, v.w));
  }
  __syncthreads();
  const int w = t >> 6, l = t & 63, l31 = l & 31, lh = l >> 5;
  f32x16 acc0, acc1;
  for (int i = 0; i < 16; ++i) { acc0[i] = 0.f; acc1[i] = 0.f; }
  const int nt0 = w * 2;
  const unsigned short* w0 = WT + (size_t)(nt0 * 32 + l31) * 512 + lh * 8;
  const unsigned short* w1 = w0 + 32 * 512;
  const char* XB = (const char*)XS + lh * 528 + l31 * 16;
#pragma unroll 4
  for (int ks = 0; ks < 32; ++ks) {
    bf16x8 Af = *(const bf16x8*)(XB + ks * 1056);
    int4 b0 = *(const int4*)(w0 + ks * 16);
    int4 b1 = *(const int4*)(w1 + ks * 16);
    acc0 = mfma(Af, b0, acc0);
    acc1 = mfma(Af, b1, acc1);
  }
#pragma unroll
  for (int reg = 0; reg < 16; ++reg) {
    const int mm = (reg & 3) + 8 * (reg >> 2) + 4 * lh;      // C/D row map
    const int sl = ((mm >> 1) & 1) * 16 + (mm & 1) * 8 + (mm >> 2);
    hP[(size_t)mt * 8192 + (nt0 * 32 + l31) * 32 + sl] = f2bf(acc0[reg]);
    hP[(size_t)mt * 8192 + ((nt0 + 1) * 32 + l31) * 32 + sl] = f2bf(acc1[reg]);
  }
}

// K2: T[n] += partial colsum of h (slot-permutation invariant).
__global__ __launch_bounds__(256) void k2_colsum(const unsigned short* __restrict__ hP,
                                                 float* __restrict__ T) {
  const int t = threadIdx.x;
  const int b = blockIdx.x;
  const int4* p = (const int4*)(hP + (size_t)b * 8192 + t * 32);
  int4 q0 = p[0], q1 = p[1], q2 = p[2], q3 = p[3];
  float s = 0.f;
  const unsigned* u0 = (const unsigned*)&q0;
  const unsigned* u1 = (const unsigned*)&q1;
  const unsigned* u2 = (const unsigned*)&q2;
  const unsigned* u3 = (const unsigned*)&q3;
#pragma unroll
  for (int i = 0; i < 4; ++i) {
    s += bfbits2f(u0[i] & 0xFFFFu) + bfbits2f(u0[i] >> 16);
    s += bfbits2f(u1[i] & 0xFFFFu) + bfbits2f(u1[i] >> 16);
    s += bfbits2f(u2[i] & 0xFFFFu) + bfbits2f(u2[i] >> 16);
    s += bfbits2f(u3[i] & 0xFFFFu) + bfbits2f(u3[i] >> 16);
  }
  atomicAdd(&T[t], s);
}

// K3: out = -9e15*(T - (adj>0)@h). Grid 512 WG x 256 thr (2 WG/CU).
// WG = tile 64r x 64c; 4 waves = splitK=4 (wave s: 64 iters of 32 j).
// All main-loop VMEM = volatile asm; hand-counted vmcnt pipeline:
// B slots 0..3 (4 iters deep, waits 16/12), bm ping-pong 1 block ahead.
__global__ __launch_bounds__(256, 2) void k3_att(
    const unsigned long long* __restrict__ bm,
    const unsigned short* __restrict__ hP, const float* __restrict__ T,
    float* __restrict__ out) {
  __shared__ float red[3][64][64];   // 48KB, epilogue only
  const int t = threadIdx.x, blk = blockIdx.x;
  const int w = t >> 6, l = t & 63, l31 = l & 31, lh = l >> 5;
  const int s = w;                   // j-split 0..3
  const int rb = blk >> 2, cb = blk & 3;
  const int r0 = rb * 64;
  const int cw0 = cb * 64;

  // bm bases: row r0+l31 (rt0) / +32 (rt1), s-slice, lh dword-pair select
  const char* pM0 = (const char*)bm + (size_t)(r0 + l31) * 1024 + s * 256 + lh * 8;
  const char* pM1 = pM0 + 32 * 1024;
  // B slot bases: lane (cw0+l31, lh), wave j-range start s*64; slot p = +p tiles
  const char* pB0 = (const char*)hP + (size_t)(cw0 + l31) * 64 + lh * 16 +
                    (size_t)(s * 64) * 16384;
  const char* pB1 = pB0 + 16384;
  const char* pB2 = pB0 + 32768;
  const char* pB3 = pB0 + 49152;

  f32x16 acc[2][2];
#pragma unroll
  for (int mt = 0; mt < 2; ++mt)
#pragma unroll
    for (int nt = 0; nt < 2; ++nt)
#pragma unroll
      for (int i = 0; i < 16; ++i) acc[mt][nt][i] = 0.f;

  int4 Bv0_0, Bv0_1, Bv0_2, Bv0_3;
  int4 Bv1_0, Bv1_1, Bv1_2, Bv1_3;
  int4 Bv2_0, Bv2_1, Bv2_2, Bv2_3;
  int4 Bv3_0, Bv3_1, Bv3_2, Bv3_3;
  uint2 mA0, mA1, mA2, mA3, mB0, mB1, mB2, mB3;

#define GLD16(dst, ptr, OFF)                                                \
  asm volatile("global_load_dwordx4 %0, %1, off offset:" #OFF               \
               : "=v"(dst) : "v"(ptr));
#define GLD8(dst, ptr, OFF)                                                 \
  asm volatile("global_load_dwordx2 %0, %1, off offset:" #OFF               \
               : "=v"(dst) : "v"(ptr));
// B slot issue: 4x dwordx4 (frag offsets 0,32,2048,2080 B), bump 4 tiles
#define STAGE_B(S)                                                          \
  GLD16(Bv##S##_0, pB##S, 0)                                                \
  GLD16(Bv##S##_1, pB##S, 32)                                               \
  GLD16(Bv##S##_2, pB##S, 2048)                                             \
  GLD16(Bv##S##_3, pB##S, 2080)                                             \
  pB##S += 65536;
// bm block issue into set SET (4x dwordx2), bump 1 block
#define STAGE_M(SET)                                                        \
  GLD8(m##SET##0, pM0, 0)                                                   \
  GLD8(m##SET##1, pM0, 16)                                                  \
  GLD8(m##SET##2, pM1, 0)                                                   \
  GLD8(m##SET##3, pM1, 16)                                                  \
  pM0 += 32; pM1 += 32;
// counted wait, operand-free; sched_barrier(0) (rule #18) pins everything
// after it — MFMA/VALU cannot hoist above the wait.
#define VWAIT(K)                                                            \
  asm volatile("s_waitcnt vmcnt(" #K ")" ::: "memory");                     \
  __builtin_amdgcn_sched_barrier(0);
// expand 8 consecutive bits (byte m3) of dword dw -> 8 bf16 {0,1} (uint4)
#define XP(dw, m3, u4)                                                      \
  {                                                                         \
    const unsigned bb_ = ((dw) >> (8 * (m3))) & 0xFFu;                      \
    const unsigned tt_ = bb_ | (bb_ << 15);                                 \
    u4.x = ((tt_)&0x00010001u) * 0x3F80u;                                   \
    u4.y = ((tt_ >> 2) & 0x00010001u) * 0x3F80u;                            \
    u4.z = ((tt_ >> 4) & 0x00010001u) * 0x3F80u;                            \
    u4.w = ((tt_ >> 6) & 0x00010001u) * 0x3F80u;                            \
  }
// one iter: counted wait (retires slot S quartet, and the bm set at
// ITER0-first-block/ITER4-steady), expand 4 A-frags from set C (masks
// pasted into uint2 locals; never m##C##0.y — "0.y" lexes as one
// pp-number and breaks the paste), 8 MFMA, re-issue slot S for it+4.
#define ITER(i, S, K, C)                                                    \
  VWAIT(K)                                                                  \
  {                                                                         \
    const uint2 c0_ = m##C##0;  /* rt0 ks0 */                               \
    const uint2 c1_ = m##C##1;  /* rt0 ks1 */                               \
    const uint2 c2_ = m##C##2;  /* rt1 ks0 */                               \
    const uint2 c3_ = m##C##3;  /* rt1 ks1 */                               \
    const unsigned d00_ = ((i) >> 2) ? c0_.y : c0_.x;                       \
    const unsigned d01_ = ((i) >> 2) ? c1_.y : c1_.x;                       \
    const unsigned d10_ = ((i) >> 2) ? c2_.y : c2_.x;                       \
    const unsigned d11_ = ((i) >> 2) ? c3_.y : c3_.x;                       \
    uint4 u00_, u01_, u10_, u11_;                                           \
    XP(d00_, (i)&3, u00_)                                                   \
    XP(d01_, (i)&3, u01_)                                                   \
    XP(d10_, (i)&3, u10_)                                                   \
    XP(d11_, (i)&3, u11_)                                                   \
    const bf16x8 A00_ = __builtin_bit_cast(bf16x8, u00_);                   \
    const bf16x8 A01_ = __builtin_bit_cast(bf16x8, u01_);                   \
    const bf16x8 A10_ = __builtin_bit_cast(bf16x8, u10_);                   \
    const bf16x8 A11_ = __builtin_bit_cast(bf16x8, u11_);                   \
    acc[0][0] = mfma(A00_, Bv##S##_0, acc[0][0]);                           \
    acc[1][0] = mfma(A10_, Bv##S##_0, acc[1][0]);                           \
    acc[0][1] = mfma(A00_, Bv##S##_2, acc[0][1]);                           \
    acc[1][1] = mfma(A10_, Bv##S##_2, acc[1][1]);                           \
    acc[0][0] = mfma(A01_, Bv##S##_1, acc[0][0]);                           \
    acc[1][0] = mfma(A11_, Bv##S##_1, acc[1][0]);                           \
    acc[0][1] = mfma(A01_, Bv##S##_3, acc[0][1]);                           \
    acc[1][1] = mfma(A11_, Bv##S##_3, acc[1][1]);                           \
  }                                                                         \
  STAGE_B(S)
// 8-iter block: stage bm(b+1) into set N, consume set C.
// vmcnt trace (simulated): prologue leaves 20 outstanding
// [bm(4), B0..B3(16)]. Block top STAGE_M -> 24. ITER0 wait(16) retires
// bm+B0 (8); each ITERk then +4/-4; ITER4 wait(12) retires next-bm+B0'.
// Steady state at every block top: 16 outstanding + STAGE_M -> 20;
// ITER0..3 wait(16) retire one B quartet each; ITER4 wait(12) retires
// bm(next)+B0'; ITER5..7 wait(12) retire one quartet each.
#define BLOCK(C, N)                                                         \
  STAGE_M(N)                                                                \
  ITER(0, 0, 16, C) ITER(1, 1, 16, C) ITER(2, 2, 16, C) ITER(3, 3, 16, C)   \
  ITER(4, 0, 12, C) ITER(5, 1, 12, C) ITER(6, 2, 12, C) ITER(7, 3, 12, C)

  // prologue: bm block 0 + B slots for iters 0..3 (20 outstanding)
  STAGE_M(A)
  STAGE_B(0) STAGE_B(1) STAGE_B(2) STAGE_B(3)

#pragma unroll 1
  for (int b2 = 0; b2 < 4; ++b2) {
    BLOCK(A, B)
    BLOCK(B, A)
  }
#undef BLOCK
#undef ITER
#undef XP
#undef VWAIT
#undef STAGE_M
#undef STAGE_B
#undef GLD8
#undef GLD16

  // drain: all in-flight asm loads complete before any epilogue code
  // (volatile-asm order holds the drain below the tail stages; the
  // sched_barrier holds the epilogue below the drain).
  asm volatile("s_waitcnt vmcnt(0)" ::: "memory");
  __builtin_amdgcn_sched_barrier(0);

  // epilogue: splitK reduce via LDS, wave 0 writes out = -9e15*(T - Am)
  if (s > 0) {
#pragma unroll
    for (int mt = 0; mt < 2; ++mt)
#pragma unroll
      for (int nt = 0; nt < 2; ++nt)
#pragma unroll
        for (int reg = 0; reg < 16; ++reg)
          red[s - 1][(mt * 2 + nt) * 16 + reg][l] = acc[mt][nt][reg];
  }
  __syncthreads();
  if (s == 0) {
#pragma unroll
    for (int mt = 0; mt < 2; ++mt)
#pragma unroll
      for (int nt = 0; nt < 2; ++nt) {
        const int cc = cw0 + nt * 32 + l31;
        const float tv = T[cc];
#pragma unroll
        for (int reg = 0; reg < 16; ++reg) {
          const int idx = (mt * 2 + nt) * 16 + reg;
          const float am = acc[mt][nt][reg] + red[0][idx][l] +
                           red[1][idx][l] + red[2][idx][l];
          const int rr = r0 + mt * 32 + (reg & 3) + 8 * (reg >> 2) + 4 * lh;
          out[(size_t)rr * 256 + cc] = NEG_BIG * (tv - am);
        }
      }
  }
}

extern "C" void kernel_launch(void* const* d_in, const int* in_sizes, int n_in,
                              void* d_out, int out_size, void* d_ws, size_t ws_size,
                              hipStream_t stream) {
  const float* x = (const float*)d_in[0];     // 8192 x 512
  const float* W = (const float*)d_in[1];     // 512 x 256
  // d_in[2] ('a') unused: its contribution is ~1e4 vs threshold ~9e16.
  const int* adj = (const int*)d_in[3];       // 8192 x 8192 int32 {0,1}
  float* out = (float*)d_out;                 // 8192 x 256 fp32
  char* ws = (char*)d_ws;
  unsigned short* WT = (unsigned short*)(ws);             // 256 KB
  unsigned short* hP = (unsigned short*)(ws + (1 << 20)); // 4 MB panel
  float* T = (float*)(ws + (6 << 20));                    // 1 KB
  unsigned long long* bm = (unsigned long long*)(ws + (8 << 20)); // 8 MB

  k0_bits<<<2048, 256, 0, stream>>>(adj, bm);
  k1a_wt<<<512, 256, 0, stream>>>(W, WT, T);
  k1b_h<<<256, 256, 0, stream>>>(x, WT, hP);
  k2_colsum<<<256, 256, 0, stream>>>(hP, T);
  k3_att<<<512, 256, 0, stream>>>(bm, hP, T, out);
}

// Round 7
// 442.784 us; speedup vs baseline: 1.0029x; 1.0029x over previous
//
#include <hip/hip_runtime.h>

// out = att @ h  with att = where(adj>0, s1[i]+s2[j], -9e15).
// out[i,k] = -9e15 * (T[k] - Am[i,k]),  Am = (adj>0) @ h,  T = colsum(h)
//
// R13 = R12 + XCD-pinned tile remap (T1). Evidence: R8/R9/R12 k3 all
// ~100us despite 3 different schedules => BW-bound, not latency/issue.
// B traffic 512MB + bm 32MB at ~5TB/s (LLC) = ~105us. Cause: every XCD
// hosts WGs of all 4 col-blocks (hP 4MB + bm 4MB > 4MB L2 => LLC serves
// the B stream). Fix: cb = (blk&7)>>1, rb = (blk>>3)+64*((blk&7)&1) —
// dispatch round-robins blk%8 across XCDs (m09/T1), so each XCD's 64 WGs
// share ONE 1MB hP slice => L2-resident; bm is one-touch (streams freely).
// Predicted: B at L2 BW (512MB ~ 15us aggregate), k3 -> ~25-35us.
//
// R12: waits are operand-free ("memory" clobber) + sched_barrier(0)
// (rule #18: the barrier stops MFMA/VALU hoisting above the wait).
// Backend rejects tied ("+v")/input ("v") VECTOR asm operands; "=v" ok.
// All main-loop VMEM is volatile inline asm, HAND-COUNTED vmcnt (never 0):
//  - B: 4 slots, 4 iters deep; steady waits vmcnt(16)/(12).
//  - bm: ping-pong sets, 1 block (8 iters) ahead; retired by ITER0
//    (first block) / ITER4 (steady) waits — trace below.
//  - final operand-free vmcnt(0) + sched_barrier before the epilogue.
// Unconditional tail prefetches read workspace padding (verified: B tail
// ends < ws+5.3MB, T at +6MB; bm tail ends ~ws+16MB+300B; ws >= 72MB).
// Geometry/expansion/epilogue identical to R9 (harness-verified).
//
// Bitmask format (per row, 32 blocks of 256 j): block b = 4 u64 [c=0..3],
// bit l of u64 c = adj[i][b*256 + 4l + c]  (ballot over int4 lanes).

#define NEG_BIG (-9000000000000000.0f)

typedef __bf16 bf16x8 __attribute__((ext_vector_type(8)));
typedef float f32x16 __attribute__((ext_vector_type(16)));

static __device__ __forceinline__ unsigned short f2bf(float f) {
  unsigned u = __builtin_bit_cast(unsigned, f);
  u = u + 0x7FFFu + ((u >> 16) & 1u);   // RNE
  return (unsigned short)(u >> 16);
}
static __device__ __forceinline__ float bfbits2f(unsigned hi16) {
  return __builtin_bit_cast(float, hi16 << 16);
}
static __device__ __forceinline__ unsigned pk2(float a, float b) {
  return (unsigned)f2bf(a) | ((unsigned)f2bf(b) << 16);
}
static __device__ __forceinline__ bf16x8 asbf(int4 q) {
  return __builtin_bit_cast(bf16x8, q);
}
static __device__ __forceinline__ f32x16 mfma(bf16x8 a, int4 b, f32x16 c) {
  return __builtin_amdgcn_mfma_f32_32x32x16_bf16(a, asbf(b), c, 0, 0, 0);
}

// K0: adj -> bitmask. Wave = one row pass; lane l reads int4 (4 j), 4
// ballots produce 256 j bits per iter. 8192 waves, 32 iters each, 32w/CU.
__global__ __launch_bounds__(256) void k0_bits(const int* __restrict__ adj,
    unsigned long long* __restrict__ bm) {
  const int w = threadIdx.x >> 6, l = threadIdx.x & 63;
  const int row = blockIdx.x * 4 + w;
  const int4* ar = (const int4*)(adj + (size_t)row * 8192) + l;
  unsigned long long* br = bm + (size_t)row * 128;
#pragma unroll 2
  for (int b = 0; b < 32; ++b) {
    int4 v = ar[b * 64];
    unsigned long long b0 = __ballot(v.x > 0);
    unsigned long long b1 = __ballot(v.y > 0);
    unsigned long long b2 = __ballot(v.z > 0);
    unsigned long long b3 = __ballot(v.w > 0);
    if (l == 0) {
      ulonglong2* p = (ulonglong2*)(br + (size_t)b * 4);
      p[0] = make_ulonglong2(b0, b1);
      p[1] = make_ulonglong2(b2, b3);
    }
  }
}

// K1a: WT[n][k] = bf16(W[k][n]); W is 512x256 row-major. Also zeroes T.
__global__ void k1a_wt(const float* __restrict__ W, unsigned short* __restrict__ WT,
                       float* __restrict__ T) {
  const int i = blockIdx.x * 256 + threadIdx.x;
  const int k = i >> 8, n = i & 255;
  WT[n * 512 + k] = f2bf(W[i]);
  if (blockIdx.x == 0) T[threadIdx.x] = 0.f;
}

// K1b: h = x @ W. x tile (32 rows x 512 k) staged through LDS in
// fragment-ready bf16 layout, then 32 MFMA k-steps. Panel slots are
// PERMUTED: physical row mm -> slot ((mm>>1)&1)*16 + (mm&1)*8 + (mm>>2)
// so k3's A-frag = consecutive bits of one ballot dword.
__global__ __launch_bounds__(256) void k1b_h(const float* __restrict__ x,
    const unsigned short* __restrict__ WT, unsigned short* __restrict__ hP) {
  __shared__ unsigned short XS[64 * 264];
  const int t = threadIdx.x;
  const int mt = blockIdx.x;
  const int m0 = mt << 5;
  const int row = t >> 3, c7 = t & 7;
  const float* xr = x + (size_t)(m0 + row) * 512 + c7 * 4;
  const int gb = c7 >> 1, off = (t & 1) * 4;
#pragma unroll
  for (int j = 0; j < 16; ++j) {
    float4 v = *(const float4*)(xr + 32 * j);
    *(uint2*)&XS[(gb + 4 * j) * 264 + row * 8 + off] =
        make_uint2(pk2(v.x, v.y), pk2(v.z, v.w));
  }
  __syncthreads();
  const int w = t >> 6, l = t & 63, l31 = l & 31, lh = l >> 5;
  f32x16 acc0, acc1;
  for (int i = 0; i < 16; ++i) { acc0[i] = 0.f; acc1[i] = 0.f; }
  const int nt0 = w * 2;
  const unsigned short* w0 = WT + (size_t)(nt0 * 32 + l31) * 512 + lh * 8;
  const unsigned short* w1 = w0 + 32 * 512;
  const char* XB = (const char*)XS + lh * 528 + l31 * 16;
#pragma unroll 4
  for (int ks = 0; ks < 32; ++ks) {
    bf16x8 Af = *(const bf16x8*)(XB + ks * 1056);
    int4 b0 = *(const int4*)(w0 + ks * 16);
    int4 b1 = *(const int4*)(w1 + ks * 16);
    acc0 = mfma(Af, b0, acc0);
    acc1 = mfma(Af, b1, acc1);
  }
#pragma unroll
  for (int reg = 0; reg < 16; ++reg) {
    const int mm = (reg & 3) + 8 * (reg >> 2) + 4 * lh;      // C/D row map
    const int sl = ((mm >> 1) & 1) * 16 + (mm & 1) * 8 + (mm >> 2);
    hP[(size_t)mt * 8192 + (nt0 * 32 + l31) * 32 + sl] = f2bf(acc0[reg]);
    hP[(size_t)mt * 8192 + ((nt0 + 1) * 32 + l31) * 32 + sl] = f2bf(acc1[reg]);
  }
}

// K2: T[n] += partial colsum of h (slot-permutation invariant).
__global__ __launch_bounds__(256) void k2_colsum(const unsigned short* __restrict__ hP,
                                                 float* __restrict__ T) {
  const int t = threadIdx.x;
  const int b = blockIdx.x;
  const int4* p = (const int4*)(hP + (size_t)b * 8192 + t * 32);
  int4 q0 = p[0], q1 = p[1], q2 = p[2], q3 = p[3];
  float s = 0.f;
  const unsigned* u0 = (const unsigned*)&q0;
  const unsigned* u1 = (const unsigned*)&q1;
  const unsigned* u2 = (const unsigned*)&q2;
  const unsigned* u3 = (const unsigned*)&q3;
#pragma unroll
  for (int i = 0; i < 4; ++i) {
    s += bfbits2f(u0[i] & 0xFFFFu) + bfbits2f(u0[i] >> 16);
    s += bfbits2f(u1[i] & 0xFFFFu) + bfbits2f(u1[i] >> 16);
    s += bfbits2f(u2[i] & 0xFFFFu) + bfbits2f(u2[i] >> 16);
    s += bfbits2f(u3[i] & 0xFFFFu) + bfbits2f(u3[i] >> 16);
  }
  atomicAdd(&T[t], s);
}

// K3: out = -9e15*(T - (adj>0)@h). Grid 512 WG x 256 thr (2 WG/CU).
// Tile map XCD-PINNED: xcd=blk&7 -> cb=xcd>>1, rb=(blk>>3)+64*(xcd&1);
// each XCD's 64 WGs share one 1MB hP slice (L2-resident). WG = 64r x 64c,
// 4 waves = splitK=4 (wave s: 64 iters of 32 j). All main-loop VMEM =
// volatile asm; hand-counted vmcnt: B slots 0..3 (4 deep, waits 16/12),
// bm ping-pong 1 block ahead.
__global__ __launch_bounds__(256, 2) void k3_att(
    const unsigned long long* __restrict__ bm,
    const unsigned short* __restrict__ hP, const float* __restrict__ T,
    float* __restrict__ out) {
  __shared__ float red[3][64][64];   // 48KB, epilogue only
  const int t = threadIdx.x, blk = blockIdx.x;
  const int w = t >> 6, l = t & 63, l31 = l & 31, lh = l >> 5;
  const int s = w;                   // j-split 0..3
  const int xcd = blk & 7;           // dispatch round-robin (m09/T1)
  const int cb = xcd >> 1;           // col-block pinned per XCD pair
  const int rb = (blk >> 3) + ((xcd & 1) << 6);   // 0..127, bijective
  const int r0 = rb * 64;
  const int cw0 = cb * 64;

  // bm bases: row r0+l31 (rt0) / +32 (rt1), s-slice, lh dword-pair select
  const char* pM0 = (const char*)bm + (size_t)(r0 + l31) * 1024 + s * 256 + lh * 8;
  const char* pM1 = pM0 + 32 * 1024;
  // B slot bases: lane (cw0+l31, lh), wave j-range start s*64; slot p = +p tiles
  const char* pB0 = (const char*)hP + (size_t)(cw0 + l31) * 64 + lh * 16 +
                    (size_t)(s * 64) * 16384;
  const char* pB1 = pB0 + 16384;
  const char* pB2 = pB0 + 32768;
  const char* pB3 = pB0 + 49152;

  f32x16 acc[2][2];
#pragma unroll
  for (int mt = 0; mt < 2; ++mt)
#pragma unroll
    for (int nt = 0; nt < 2; ++nt)
#pragma unroll
      for (int i = 0; i < 16; ++i) acc[mt][nt][i] = 0.f;

  int4 Bv0_0, Bv0_1, Bv0_2, Bv0_3;
  int4 Bv1_0, Bv1_1, Bv1_2, Bv1_3;
  int4 Bv2_0, Bv2_1, Bv2_2, Bv2_3;
  int4 Bv3_0, Bv3_1, Bv3_2, Bv3_3;
  uint2 mA0, mA1, mA2, mA3, mB0, mB1, mB2, mB3;

#define GLD16(dst, ptr, OFF)                                                \
  asm volatile("global_load_dwordx4 %0, %1, off offset:" #OFF               \
               : "=v"(dst) : "v"(ptr));
#define GLD8(dst, ptr, OFF)                                                 \
  asm volatile("global_load_dwordx2 %0, %1, off offset:" #OFF               \
               : "=v"(dst) : "v"(ptr));
// B slot issue: 4x dwordx4 (frag offsets 0,32,2048,2080 B), bump 4 tiles
#define STAGE_B(S)                                                          \
  GLD16(Bv##S##_0, pB##S, 0)                                                \
  GLD16(Bv##S##_1, pB##S, 32)                                               \
  GLD16(Bv##S##_2, pB##S, 2048)                                             \
  GLD16(Bv##S##_3, pB##S, 2080)                                             \
  pB##S += 65536;
// bm block issue into set SET (4x dwordx2), bump 1 block
#define STAGE_M(SET)                                                        \
  GLD8(m##SET##0, pM0, 0)                                                   \
  GLD8(m##SET##1, pM0, 16)                                                  \
  GLD8(m##SET##2, pM1, 0)                                                   \
  GLD8(m##SET##3, pM1, 16)                                                  \
  pM0 += 32; pM1 += 32;
// counted wait, operand-free; sched_barrier(0) (rule #18) pins everything
// after it — MFMA/VALU cannot hoist above the wait.
#define VWAIT(K)                                                            \
  asm volatile("s_waitcnt vmcnt(" #K ")" ::: "memory");                     \
  __builtin_amdgcn_sched_barrier(0);
// expand 8 consecutive bits (byte m3) of dword dw -> 8 bf16 {0,1} (uint4)
#define XP(dw, m3, u4)                                                      \
  {                                                                         \
    const unsigned bb_ = ((dw) >> (8 * (m3))) & 0xFFu;                      \
    const unsigned tt_ = bb_ | (bb_ << 15);                                 \
    u4.x = ((tt_)&0x00010001u) * 0x3F80u;                                   \
    u4.y = ((tt_ >> 2) & 0x00010001u) * 0x3F80u;                            \
    u4.z = ((tt_ >> 4) & 0x00010001u) * 0x3F80u;                            \
    u4.w = ((tt_ >> 6) & 0x00010001u) * 0x3F80u;                            \
  }
// one iter: counted wait (retires slot S quartet, and the bm set at
// ITER0-first-block/ITER4-steady), expand 4 A-frags from set C (masks
// pasted into uint2 locals; never m##C##0.y — "0.y" lexes as one
// pp-number and breaks the paste), 8 MFMA, re-issue slot S for it+4.
#define ITER(i, S, K, C)                                                    \
  VWAIT(K)                                                                  \
  {                                                                         \
    const uint2 c0_ = m##C##0;  /* rt0 ks0 */                               \
    const uint2 c1_ = m##C##1;  /* rt0 ks1 */                               \
    const uint2 c2_ = m##C##2;  /* rt1 ks0 */                               \
    const uint2 c3_ = m##C##3;  /* rt1 ks1 */                               \
    const unsigned d00_ = ((i) >> 2) ? c0_.y : c0_.x;                       \
    const unsigned d01_ = ((i) >> 2) ? c1_.y : c1_.x;                       \
    const unsigned d10_ = ((i) >> 2) ? c2_.y : c2_.x;                       \
    const unsigned d11_ = ((i) >> 2) ? c3_.y : c3_.x;                       \
    uint4 u00_, u01_, u10_, u11_;                                           \
    XP(d00_, (i)&3, u00_)                                                   \
    XP(d01_, (i)&3, u01_)                                                   \
    XP(d10_, (i)&3, u10_)                                                   \
    XP(d11_, (i)&3, u11_)                                                   \
    const bf16x8 A00_ = __builtin_bit_cast(bf16x8, u00_);                   \
    const bf16x8 A01_ = __builtin_bit_cast(bf16x8, u01_);                   \
    const bf16x8 A10_ = __builtin_bit_cast(bf16x8, u10_);                   \
    const bf16x8 A11_ = __builtin_bit_cast(bf16x8, u11_);                   \
    acc[0][0] = mfma(A00_, Bv##S##_0, acc[0][0]);                           \
    acc[1][0] = mfma(A10_, Bv##S##_0, acc[1][0]);                           \
    acc[0][1] = mfma(A00_, Bv##S##_2, acc[0][1]);                           \
    acc[1][1] = mfma(A10_, Bv##S##_2, acc[1][1]);                           \
    acc[0][0] = mfma(A01_, Bv##S##_1, acc[0][0]);                           \
    acc[1][0] = mfma(A11_, Bv##S##_1, acc[1][0]);                           \
    acc[0][1] = mfma(A01_, Bv##S##_3, acc[0][1]);                           \
    acc[1][1] = mfma(A11_, Bv##S##_3, acc[1][1]);                           \
  }                                                                         \
  STAGE_B(S)
// 8-iter block: stage bm(b+1) into set N, consume set C.
// vmcnt trace: prologue leaves 20 outstanding [bm(4), B0..B3(16)].
// Block top STAGE_M -> 24. ITER0 wait(16) retires bm+B0 (8); each ITERk
// then +4/-4; ITER4 wait(12) retires next-bm+B0'. Steady state at block
// top: 16 + STAGE_M -> 20; ITER0..3 wait(16) retire one quartet each;
// ITER4 wait(12) retires bm(next)+B0'; ITER5..7 wait(12) one each.
#define BLOCK(C, N)                                                         \
  STAGE_M(N)                                                                \
  ITER(0, 0, 16, C) ITER(1, 1, 16, C) ITER(2, 2, 16, C) ITER(3, 3, 16, C)   \
  ITER(4, 0, 12, C) ITER(5, 1, 12, C) ITER(6, 2, 12, C) ITER(7, 3, 12, C)

  // prologue: bm block 0 + B slots for iters 0..3 (20 outstanding)
  STAGE_M(A)
  STAGE_B(0) STAGE_B(1) STAGE_B(2) STAGE_B(3)

#pragma unroll 1
  for (int b2 = 0; b2 < 4; ++b2) {
    BLOCK(A, B)
    BLOCK(B, A)
  }
#undef BLOCK
#undef ITER
#undef XP
#undef VWAIT
#undef STAGE_M
#undef STAGE_B
#undef GLD8
#undef GLD16

  // drain: all in-flight asm loads complete before any epilogue code
  asm volatile("s_waitcnt vmcnt(0)" ::: "memory");
  __builtin_amdgcn_sched_barrier(0);

  // epilogue: splitK reduce via LDS, wave 0 writes out = -9e15*(T - Am)
  if (s > 0) {
#pragma unroll
    for (int mt = 0; mt < 2; ++mt)
#pragma unroll
      for (int nt = 0; nt < 2; ++nt)
#pragma unroll
        for (int reg = 0; reg < 16; ++reg)
          red[s - 1][(mt * 2 + nt) * 16 + reg][l] = acc[mt][nt][reg];
  }
  __syncthreads();
  if (s == 0) {
#pragma unroll
    for (int mt = 0; mt < 2; ++mt)
#pragma unroll
      for (int nt = 0; nt < 2; ++nt) {
        const int cc = cw0 + nt * 32 + l31;
        const float tv = T[cc];
#pragma unroll
        for (int reg = 0; reg < 16; ++reg) {
          const int idx = (mt * 2 + nt) * 16 + reg;
          const float am = acc[mt][nt][reg] + red[0][idx][l] +
                           red[1][idx][l] + red[2][idx][l];
          const int rr = r0 + mt * 32 + (reg & 3) + 8 * (reg >> 2) + 4 * lh;
          out[(size_t)rr * 256 + cc] = NEG_BIG * (tv - am);
        }
      }
  }
}

extern "C" void kernel_launch(void* const* d_in, const int* in_sizes, int n_in,
                              void* d_out, int out_size, void* d_ws, size_t ws_size,
                              hipStream_t stream) {
  const float* x = (const float*)d_in[0];     // 8192 x 512
  const float* W = (const float*)d_in[1];     // 512 x 256
  // d_in[2] ('a') unused: its contribution is ~1e4 vs threshold ~9e16.
  const int* adj = (const int*)d_in[3];       // 8192 x 8192 int32 {0,1}
  float* out = (float*)d_out;                 // 8192 x 256 fp32
  char* ws = (char*)d_ws;
  unsigned short* WT = (unsigned short*)(ws);             // 256 KB
  unsigned short* hP = (unsigned short*)(ws + (1 << 20)); // 4 MB panel
  float* T = (float*)(ws + (6 << 20));                    // 1 KB
  unsigned long long* bm = (unsigned long long*)(ws + (8 << 20)); // 8 MB

  k0_bits<<<2048, 256, 0, stream>>>(adj, bm);
  k1a_wt<<<512, 256, 0, stream>>>(W, WT, T);
  k1b_h<<<256, 256, 0, stream>>>(x, WT, hP);
  k2_colsum<<<256, 256, 0, stream>>>(hP, T);
  k3_att<<<512, 256, 0, stream>>>(bm, hP, T, out);
}

// Round 8
// 440.986 us; speedup vs baseline: 1.0070x; 1.0041x over previous
//
#include <hip/hip_runtime.h>

// out = att @ h  with att = where(adj>0, s1[i]+s2[j], -9e15).
// out[i,k] = -9e15 * (T[k] - Am[i,k]),  Am = (adj>0) @ h,  T = colsum(h)
//
// R14: R9/R12/R13 all null (442+-1.5us) => every latency/schedule/L2 theory
// falsified. Last live lever: total B volume (512 WGs x 1MB = 512MB,
// invariant across R8-R13). This round: WG = 512 thr = 8 waves =
// 2 row-halves x splitK-4, tile 128r x 64c, grid 256 (1 WG/CU, 2 w/SIMD,
// LDS 96KB). B volume halves to 256MB; row-half wave pairs read IDENTICAL
// B addresses (L1 x2). Inner loop = verified R12 counted-vmcnt pipeline,
// unchanged. Also: k2 fused into k1b (bf16-rounded colsum, T identical),
// one fewer dispatch. Decision rule: total ~442 again => k3 is small, the
// residual is harness fill/restore + k0 at HBM roofline => ROOFLINE.
//
// R12 machinery (verified): waits operand-free + sched_barrier(0) (rule
// #18); backend rejects tied/input VECTOR asm operands, "=v" ok. All
// main-loop VMEM volatile asm, HAND-COUNTED vmcnt (never 0): B 4 slots
// 4 iters deep (waits 16/12); bm ping-pong 1 block ahead (retired by
// ITER0 first-block / ITER4 steady). Tail prefetches land in ws padding
// (B < ws+5.3MB, T at +6MB; bm tail < ws+16MB+1KB; ws >= 24MB). XCD pin:
// cb = (blk&7)>>1, rb = (blk>>3)+32*((blk&7)&1) — 32 WGs/XCD share one
// 1MB hP slice.
//
// Bitmask format (per row, 32 blocks of 256 j): block b = 4 u64 [c=0..3],
// bit l of u64 c = adj[i][b*256 + 4l + c]  (ballot over int4 lanes).

#define NEG_BIG (-9000000000000000.0f)

typedef __bf16 bf16x8 __attribute__((ext_vector_type(8)));
typedef float f32x16 __attribute__((ext_vector_type(16)));

static __device__ __forceinline__ unsigned short f2bf(float f) {
  unsigned u = __builtin_bit_cast(unsigned, f);
  u = u + 0x7FFFu + ((u >> 16) & 1u);   // RNE
  return (unsigned short)(u >> 16);
}
static __device__ __forceinline__ float bfbits2f(unsigned hi16) {
  return __builtin_bit_cast(float, hi16 << 16);
}
static __device__ __forceinline__ unsigned pk2(float a, float b) {
  return (unsigned)f2bf(a) | ((unsigned)f2bf(b) << 16);
}
static __device__ __forceinline__ bf16x8 asbf(int4 q) {
  return __builtin_bit_cast(bf16x8, q);
}
static __device__ __forceinline__ f32x16 mfma(bf16x8 a, int4 b, f32x16 c) {
  return __builtin_amdgcn_mfma_f32_32x32x16_bf16(a, asbf(b), c, 0, 0, 0);
}

// K0: adj -> bitmask. Wave = one row pass; lane l reads int4 (4 j), 4
// ballots produce 256 j bits per iter. 8192 waves, 32 iters each, 32w/CU.
__global__ __launch_bounds__(256) void k0_bits(const int* __restrict__ adj,
    unsigned long long* __restrict__ bm) {
  const int w = threadIdx.x >> 6, l = threadIdx.x & 63;
  const int row = blockIdx.x * 4 + w;
  const int4* ar = (const int4*)(adj + (size_t)row * 8192) + l;
  unsigned long long* br = bm + (size_t)row * 128;
#pragma unroll 2
  for (int b = 0; b < 32; ++b) {
    int4 v = ar[b * 64];
    unsigned long long b0 = __ballot(v.x > 0);
    unsigned long long b1 = __ballot(v.y > 0);
    unsigned long long b2 = __ballot(v.z > 0);
    unsigned long long b3 = __ballot(v.w > 0);
    if (l == 0) {
      ulonglong2* p = (ulonglong2*)(br + (size_t)b * 4);
      p[0] = make_ulonglong2(b0, b1);
      p[1] = make_ulonglong2(b2, b3);
    }
  }
}

// K1a: WT[n][k] = bf16(W[k][n]); W is 512x256 row-major. Also zeroes T.
__global__ void k1a_wt(const float* __restrict__ W, unsigned short* __restrict__ WT,
                       float* __restrict__ T) {
  const int i = blockIdx.x * 256 + threadIdx.x;
  const int k = i >> 8, n = i & 255;
  WT[n * 512 + k] = f2bf(W[i]);
  if (blockIdx.x == 0) T[threadIdx.x] = 0.f;
}

// K1b: h = x @ W (+ fused colsum -> T). x tile (32 rows x 512 k) staged
// through LDS in fragment-ready bf16 layout, then 32 MFMA k-steps. Panel
// slots PERMUTED: row mm -> slot ((mm>>1)&1)*16 + (mm&1)*8 + (mm>>2) so
// k3's A-frag = consecutive bits of one ballot dword. Colsum accumulates
// the BF16-ROUNDED values (T identical to the old k2 from hP), wave-
// reduced lh0+lh1 then one atomicAdd per col per wave.
__global__ __launch_bounds__(256) void k1b_h(const float* __restrict__ x,
    const unsigned short* __restrict__ WT, unsigned short* __restrict__ hP,
    float* __restrict__ T) {
  __shared__ unsigned short XS[64 * 264];
  const int t = threadIdx.x;
  const int mt = blockIdx.x;
  const int m0 = mt << 5;
  const int row = t >> 3, c7 = t & 7;
  const float* xr = x + (size_t)(m0 + row) * 512 + c7 * 4;
  const int gb = c7 >> 1, off = (t & 1) * 4;
#pragma unroll
  for (int j = 0; j < 16; ++j) {
    float4 v = *(const float4*)(xr + 32 * j);
    *(uint2*)&XS[(gb + 4 * j) * 264 + row * 8 + off] =
        make_uint2(pk2(v.x, v.y), pk2(v.z, v.w));
  }
  __syncthreads();
  const int w = t >> 6, l = t & 63, l31 = l & 31, lh = l >> 5;
  f32x16 acc0, acc1;
  for (int i = 0; i < 16; ++i) { acc0[i] = 0.f; acc1[i] = 0.f; }
  const int nt0 = w * 2;
  const unsigned short* w0 = WT + (size_t)(nt0 * 32 + l31) * 512 + lh * 8;
  const unsigned short* w1 = w0 + 32 * 512;
  const char* XB = (const char*)XS + lh * 528 + l31 * 16;
#pragma unroll 4
  for (int ks = 0; ks < 32; ++ks) {
    bf16x8 Af = *(const bf16x8*)(XB + ks * 1056);
    int4 b0 = *(const int4*)(w0 + ks * 16);
    int4 b1 = *(const int4*)(w1 + ks * 16);
    acc0 = mfma(Af, b0, acc0);
    acc1 = mfma(Af, b1, acc1);
  }
  float cs0 = 0.f, cs1 = 0.f;
#pragma unroll
  for (int reg = 0; reg < 16; ++reg) {
    const int mm = (reg & 3) + 8 * (reg >> 2) + 4 * lh;      // C/D row map
    const int sl = ((mm >> 1) & 1) * 16 + (mm & 1) * 8 + (mm >> 2);
    const unsigned short h0 = f2bf(acc0[reg]);
    const unsigned short h1 = f2bf(acc1[reg]);
    hP[(size_t)mt * 8192 + (nt0 * 32 + l31) * 32 + sl] = h0;
    hP[(size_t)mt * 8192 + ((nt0 + 1) * 32 + l31) * 32 + sl] = h1;
    cs0 += bfbits2f(h0);
    cs1 += bfbits2f(h1);
  }
  cs0 += __shfl_down(cs0, 32, 64);
  cs1 += __shfl_down(cs1, 32, 64);
  if (lh == 0) {
    atomicAdd(&T[nt0 * 32 + l31], cs0);
    atomicAdd(&T[(nt0 + 1) * 32 + l31], cs1);
  }
}

// K3: out = -9e15*(T - (adj>0)@h). Grid 256 WG x 512 thr (1 WG/CU,
// 2 waves/SIMD). WG tile = 128r x 64c: 8 waves = 2 row-halves (rt2) x
// splitK-4 (s: 64 iters of 32 j). B volume 256MB (halved); row-half wave
// pairs share B addresses (L1 x2). XCD-pinned: 32 WGs/XCD share one 1MB
// hP slice. Inner loop: R12 counted-vmcnt pipeline, unchanged.
__global__ __launch_bounds__(512, 1) void k3_att(
    const unsigned long long* __restrict__ bm,
    const unsigned short* __restrict__ hP, const float* __restrict__ T,
    float* __restrict__ out) {
  __shared__ float red[2][3][64][64];   // 96KB, epilogue only
  const int t = threadIdx.x, blk = blockIdx.x;
  const int w = t >> 6, l = t & 63, l31 = l & 31, lh = l >> 5;
  const int s = w & 3;               // j-split 0..3
  const int rt2 = w >> 2;            // row half 0..1
  const int xcd = blk & 7;           // dispatch round-robin (m09/T1)
  const int cb = xcd >> 1;           // col-block pinned per XCD pair
  const int rb = (blk >> 3) + ((xcd & 1) << 5);   // 0..63, bijective
  const int r0 = rb * 128 + rt2 * 64;
  const int cw0 = cb * 64;

  // bm bases: row r0+l31 (rt0) / +32 (rt1), s-slice, lh dword-pair select
  const char* pM0 = (const char*)bm + (size_t)(r0 + l31) * 1024 + s * 256 + lh * 8;
  const char* pM1 = pM0 + 32 * 1024;
  // B slot bases: lane (cw0+l31, lh), wave j-range start s*64; slot p = +p tiles
  const char* pB0 = (const char*)hP + (size_t)(cw0 + l31) * 64 + lh * 16 +
                    (size_t)(s * 64) * 16384;
  const char* pB1 = pB0 + 16384;
  const char* pB2 = pB0 + 32768;
  const char* pB3 = pB0 + 49152;

  f32x16 acc[2][2];
#pragma unroll
  for (int mt = 0; mt < 2; ++mt)
#pragma unroll
    for (int nt = 0; nt < 2; ++nt)
#pragma unroll
      for (int i = 0; i < 16; ++i) acc[mt][nt][i] = 0.f;

  int4 Bv0_0, Bv0_1, Bv0_2, Bv0_3;
  int4 Bv1_0, Bv1_1, Bv1_2, Bv1_3;
  int4 Bv2_0, Bv2_1, Bv2_2, Bv2_3;
  int4 Bv3_0, Bv3_1, Bv3_2, Bv3_3;
  uint2 mA0, mA1, mA2, mA3, mB0, mB1, mB2, mB3;

#define GLD16(dst, ptr, OFF)                                                \
  asm volatile("global_load_dwordx4 %0, %1, off offset:" #OFF               \
               : "=v"(dst) : "v"(ptr));
#define GLD8(dst, ptr, OFF)                                                 \
  asm volatile("global_load_dwordx2 %0, %1, off offset:" #OFF               \
               : "=v"(dst) : "v"(ptr));
// B slot issue: 4x dwordx4 (frag offsets 0,32,2048,2080 B), bump 4 tiles
#define STAGE_B(S)                                                          \
  GLD16(Bv##S##_0, pB##S, 0)                                                \
  GLD16(Bv##S##_1, pB##S, 32)                                               \
  GLD16(Bv##S##_2, pB##S, 2048)                                             \
  GLD16(Bv##S##_3, pB##S, 2080)                                             \
  pB##S += 65536;
// bm block issue into set SET (4x dwordx2), bump 1 block
#define STAGE_M(SET)                                                        \
  GLD8(m##SET##0, pM0, 0)                                                   \
  GLD8(m##SET##1, pM0, 16)                                                  \
  GLD8(m##SET##2, pM1, 0)                                                   \
  GLD8(m##SET##3, pM1, 16)                                                  \
  pM0 += 32; pM1 += 32;
// counted wait, operand-free; sched_barrier(0) (rule #18) pins everything
// after it — MFMA/VALU cannot hoist above the wait.
#define VWAIT(K)                                                            \
  asm volatile("s_waitcnt vmcnt(" #K ")" ::: "memory");                     \
  __builtin_amdgcn_sched_barrier(0);
// expand 8 consecutive bits (byte m3) of dword dw -> 8 bf16 {0,1} (uint4)
#define XP(dw, m3, u4)                                                      \
  {                                                                         \
    const unsigned bb_ = ((dw) >> (8 * (m3))) & 0xFFu;                      \
    const unsigned tt_ = bb_ | (bb_ << 15);                                 \
    u4.x = ((tt_)&0x00010001u) * 0x3F80u;                                   \
    u4.y = ((tt_ >> 2) & 0x00010001u) * 0x3F80u;                            \
    u4.z = ((tt_ >> 4) & 0x00010001u) * 0x3F80u;                            \
    u4.w = ((tt_ >> 6) & 0x00010001u) * 0x3F80u;                            \
  }
// one iter: counted wait (retires slot S quartet, and the bm set at
// ITER0-first-block/ITER4-steady), expand 4 A-frags from set C (masks
// pasted into uint2 locals; never m##C##0.y — "0.y" lexes as one
// pp-number and breaks the paste), 8 MFMA, re-issue slot S for it+4.
#define ITER(i, S, K, C)                                                    \
  VWAIT(K)                                                                  \
  {                                                                         \
    const uint2 c0_ = m##C##0;  /* rt0 ks0 */                               \
    const uint2 c1_ = m##C##1;  /* rt0 ks1 */                               \
    const uint2 c2_ = m##C##2;  /* rt1 ks0 */                               \
    const uint2 c3_ = m##C##3;  /* rt1 ks1 */                               \
    const unsigned d00_ = ((i) >> 2) ? c0_.y : c0_.x;                       \
    const unsigned d01_ = ((i) >> 2) ? c1_.y : c1_.x;                       \
    const unsigned d10_ = ((i) >> 2) ? c2_.y : c2_.x;                       \
    const unsigned d11_ = ((i) >> 2) ? c3_.y : c3_.x;                       \
    uint4 u00_, u01_, u10_, u11_;                                           \
    XP(d00_, (i)&3, u00_)                                                   \
    XP(d01_, (i)&3, u01_)                                                   \
    XP(d10_, (i)&3, u10_)                                                   \
    XP(d11_, (i)&3, u11_)                                                   \
    const bf16x8 A00_ = __builtin_bit_cast(bf16x8, u00_);                   \
    const bf16x8 A01_ = __builtin_bit_cast(bf16x8, u01_);                   \
    const bf16x8 A10_ = __builtin_bit_cast(bf16x8, u10_);                   \
    const bf16x8 A11_ = __builtin_bit_cast(bf16x8, u11_);                   \
    acc[0][0] = mfma(A00_, Bv##S##_0, acc[0][0]);                           \
    acc[1][0] = mfma(A10_, Bv##S##_0, acc[1][0]);                           \
    acc[0][1] = mfma(A00_, Bv##S##_2, acc[0][1]);                           \
    acc[1][1] = mfma(A10_, Bv##S##_2, acc[1][1]);                           \
    acc[0][0] = mfma(A01_, Bv##S##_1, acc[0][0]);                           \
    acc[1][0] = mfma(A11_, Bv##S##_1, acc[1][0]);                           \
    acc[0][1] = mfma(A01_, Bv##S##_3, acc[0][1]);                           \
    acc[1][1] = mfma(A11_, Bv##S##_3, acc[1][1]);                           \
  }                                                                         \
  STAGE_B(S)
// 8-iter block: stage bm(b+1) into set N, consume set C.
// vmcnt trace: prologue leaves 20 outstanding [bm(4), B0..B3(16)].
// Block top STAGE_M -> 24. ITER0 wait(16) retires bm+B0 (8); each ITERk
// then +4/-4; ITER4 wait(12) retires next-bm+B0'. Steady state at block
// top: 16 + STAGE_M -> 20; ITER0..3 wait(16) retire one quartet each;
// ITER4 wait(12) retires bm(next)+B0'; ITER5..7 wait(12) one each.
#define BLOCK(C, N)                                                         \
  STAGE_M(N)                                                                \
  ITER(0, 0, 16, C) ITER(1, 1, 16, C) ITER(2, 2, 16, C) ITER(3, 3, 16, C)   \
  ITER(4, 0, 12, C) ITER(5, 1, 12, C) ITER(6, 2, 12, C) ITER(7, 3, 12, C)

  // prologue: bm block 0 + B slots for iters 0..3 (20 outstanding)
  STAGE_M(A)
  STAGE_B(0) STAGE_B(1) STAGE_B(2) STAGE_B(3)

#pragma unroll 1
  for (int b2 = 0; b2 < 4; ++b2) {
    BLOCK(A, B)
    BLOCK(B, A)
  }
#undef BLOCK
#undef ITER
#undef XP
#undef VWAIT
#undef STAGE_M
#undef STAGE_B
#undef GLD8
#undef GLD16

  // drain: all in-flight asm loads complete before any epilogue code
  asm volatile("s_waitcnt vmcnt(0)" ::: "memory");
  __builtin_amdgcn_sched_barrier(0);

  // epilogue: per row-half, splitK reduce via LDS; s==0 waves write
  // out = -9e15*(T - Am) for their 64 rows x 64 cols.
  if (s > 0) {
#pragma unroll
    for (int mt = 0; mt < 2; ++mt)
#pragma unroll
      for (int nt = 0; nt < 2; ++nt)
#pragma unroll
        for (int reg = 0; reg < 16; ++reg)
          red[rt2][s - 1][(mt * 2 + nt) * 16 + reg][l] = acc[mt][nt][reg];
  }
  __syncthreads();
  if (s == 0) {
#pragma unroll
    for (int mt = 0; mt < 2; ++mt)
#pragma unroll
      for (int nt = 0; nt < 2; ++nt) {
        const int cc = cw0 + nt * 32 + l31;
        const float tv = T[cc];
#pragma unroll
        for (int reg = 0; reg < 16; ++reg) {
          const int idx = (mt * 2 + nt) * 16 + reg;
          const float am = acc[mt][nt][reg] + red[rt2][0][idx][l] +
                           red[rt2][1][idx][l] + red[rt2][2][idx][l];
          const int rr = r0 + mt * 32 + (reg & 3) + 8 * (reg >> 2) + 4 * lh;
          out[(size_t)rr * 256 + cc] = NEG_BIG * (tv - am);
        }
      }
  }
}

extern "C" void kernel_launch(void* const* d_in, const int* in_sizes, int n_in,
                              void* d_out, int out_size, void* d_ws, size_t ws_size,
                              hipStream_t stream) {
  const float* x = (const float*)d_in[0];     // 8192 x 512
  const float* W = (const float*)d_in[1];     // 512 x 256
  // d_in[2] ('a') unused: its contribution is ~1e4 vs threshold ~9e16.
  const int* adj = (const int*)d_in[3];       // 8192 x 8192 int32 {0,1}
  float* out = (float*)d_out;                 // 8192 x 256 fp32
  char* ws = (char*)d_ws;
  unsigned short* WT = (unsigned short*)(ws);             // 256 KB
  unsigned short* hP = (unsigned short*)(ws + (1 << 20)); // 4 MB panel
  float* T = (float*)(ws + (6 << 20));                    // 1 KB
  unsigned long long* bm = (unsigned long long*)(ws + (8 << 20)); // 8 MB

  k0_bits<<<2048, 256, 0, stream>>>(adj, bm);
  k1a_wt<<<512, 256, 0, stream>>>(W, WT, T);
  k1b_h<<<256, 256, 0, stream>>>(x, WT, hP, T);
  k3_att<<<256, 512, 0, stream>>>(bm, hP, T, out);
}